// Round 1
// baseline (1152.004 us; speedup 1.0000x reference)
//
#include <hip/hip_runtime.h>
#include <math.h>

// ---- problem constants ----
#define D    128
#define TT   128
#define E    100
#define NHD  2
#define BSZ  2048
#define N0C  6144
#define K0C  5
#define N1C  30720
#define K1C  10
#define NNC  200000
#define MC   4096
#define MSG  484
#define KIN  356        // D+E+T
#define HSTR 357        // per-head qw stride (356 cols + qb)
#define QWROW 714       // 2*HSTR

__device__ __forceinline__ float sigmoidf_(float x){ return 1.f/(1.f+__expf(-x)); }

// ---------- precompute: qc (time-const query bias), cb (fused out bias) ----------
__global__ void k_pre_small(const float* time_b,
                            const float* Wq0,const float* bq0,const float* Wq1,const float* bq1,
                            const float* bv0,const float* Wo0,const float* bo0,
                            const float* bv1,const float* Wo1,const float* bo1,
                            float* qc0, float* qc1, float* cb0, float* cb1){
    __shared__ float cosb[TT];
    int j = threadIdx.x; // 128 threads
    cosb[j] = cosf(time_b[j]);
    __syncthreads();
    float a0=bq0[j], a1=bq1[j];
    for(int t=0;t<TT;++t){ a0 += cosb[t]*Wq0[(D+t)*D + j]; a1 += cosb[t]*Wq1[(D+t)*D + j]; }
    qc0[j]=a0; qc1[j]=a1;
    float c0=bo0[j], c1=bo1[j];
    for(int jp=0;jp<D;++jp){ c0 += bv0[jp]*Wo0[jp*D + j]; c1 += bv1[jp]*Wo1[jp*D + j]; }
    cb0[j]=c0; cb1[j]=c1;
}

// WkT[j*357+c] = Wk[c][j] (c<356), col 356 = bk[j]
__global__ void k_wkT(const float* Wk0,const float* bk0,const float* Wk1,const float* bk1,
                      float* WkT0, float* WkT1){
    int l = blockIdx.x / HSTR; int c = blockIdx.x % HSTR; int j = threadIdx.x;
    const float* Wk = l? Wk1:Wk0; const float* bk = l? bk1:bk0; float* WkT = l? WkT1:WkT0;
    WkT[j*HSTR + c] = (c < KIN) ? Wk[c*D + j] : bk[j];
}

// Wvo[(h*356+c)*128+j] = sum_d Wv[c][h*64+d] * Wo[h*64+d][j]
__global__ void k_wvo(const float* Wv0,const float* Wo0,const float* Wv1,const float* Wo1,
                      float* Wvo0, float* Wvo1){
    int l = blockIdx.x / (2*KIN); int r = blockIdx.x % (2*KIN);
    int h = r/KIN; int c = r%KIN; int j = threadIdx.x;
    const float* Wv = l? Wv1:Wv0; const float* Wo = l? Wo1:Wo0; float* Wvo = l? Wvo1:Wvo0;
    float a = 0.f;
    for(int d=0; d<64; ++d) a += Wv[c*D + h*64+d] * Wo[(h*64+d)*D + j];
    Wvo[(size_t)r*D + j] = a;
}

// ---------- GRU memory update on M rows ----------
__global__ void k_map_init(int* map){ int i = blockIdx.x*256+threadIdx.x; if(i<NNC) map[i] = -1; }
__global__ void k_map_scatter(const int* msg_nids, int* map){
    int i = blockIdx.x*256+threadIdx.x; if(i<MC) map[msg_nids[i]] = i;
}

__global__ __launch_bounds__(128) void k_gru(const float* msgs, const float* memory, const int* msg_nids,
                      const float* Wih, const float* bih, const float* Whh, const float* bhh,
                      float* upd){
    __shared__ float xs[16*MSG];
    __shared__ float hs[16*D];
    int blk = blockIdx.x; int tid = threadIdx.x;
    const float* mrow = msgs + (size_t)blk*16*MSG;
    for(int idx=tid; idx<16*MSG; idx+=128) xs[idx] = mrow[idx];
    for(int idx=tid; idx<16*D; idx+=128){
        int m = idx>>7; int c = idx&127;
        int nid = msg_nids[blk*16+m];
        hs[idx] = memory[(size_t)nid*D + c];
    }
    __syncthreads();
    int d = tid;
    float r[16], u[16], nn[16];
    for(int g=0; g<3; ++g){
        float ai[16], ah[16];
        #pragma unroll
        for(int m=0;m<16;++m){ ai[m]=0.f; ah[m]=0.f; }
        const float* wi = Wih + (size_t)(g*D+d)*MSG;
        for(int c=0;c<MSG;++c){ float w = wi[c];
            #pragma unroll
            for(int m=0;m<16;++m) ai[m] += w * xs[m*MSG + c]; }
        const float* wh = Whh + (size_t)(g*D+d)*D;
        for(int c=0;c<D;++c){ float w = wh[c];
            #pragma unroll
            for(int m=0;m<16;++m) ah[m] += w * hs[m*D + c]; }
        float bi = bih[g*D+d], bh = bhh[g*D+d];
        if(g==0){
            #pragma unroll
            for(int m=0;m<16;++m) r[m] = sigmoidf_(ai[m]+bi+ah[m]+bh);
        } else if(g==1){
            #pragma unroll
            for(int m=0;m<16;++m) u[m] = sigmoidf_(ai[m]+bi+ah[m]+bh);
        } else {
            #pragma unroll
            for(int m=0;m<16;++m) nn[m] = tanhf(ai[m]+bi + r[m]*(ah[m]+bh));
        }
    }
    #pragma unroll
    for(int m=0;m<16;++m)
        upd[(size_t)(blk*16+m)*D + d] = (1.f-u[m])*nn[m] + u[m]*hs[m*D+d];
}

// gather node memories through the update map
__global__ void k_gather(const int* seed, const int* map, const float* memory, const float* upd,
                         float* hout, int nelem){
    int i = blockIdx.x*256 + threadIdx.x;
    if(i >= nelem) return;
    int row = i>>7, c = i&127;
    int sid = seed[row];
    int mi = map[sid];
    hout[i] = (mi>=0) ? upd[(size_t)mi*D + c] : memory[(size_t)sid*D + c];
}

// q = h @ Wq[0:128] + qc   (32 nodes / block)
__global__ __launch_bounds__(256) void k_qproj(const float* h, const float* Wq, const float* qc, float* q){
    __shared__ float hls[32*D];
    int blk = blockIdx.x;
    const float* hrow = h + (size_t)blk*32*D;
    for(int idx=threadIdx.x; idx<32*D; idx+=256) hls[idx]=hrow[idx];
    __syncthreads();
    int j = threadIdx.x & 127; int g = threadIdx.x >> 7;
    float acc[16];
    #pragma unroll
    for(int m=0;m<16;++m) acc[m]=0.f;
    for(int c=0;c<D;++c){
        float w = Wq[c*D + j];
        #pragma unroll
        for(int m=0;m<16;++m) acc[m] += hls[(g*16+m)*D + c] * w;
    }
    float qcj = qc[j];
    float* qrow = q + (size_t)blk*32*D;
    #pragma unroll
    for(int m=0;m<16;++m) qrow[(g*16+m)*D + j] = acc[m] + qcj;
}

// qw[n, h*357+c] = sum_d q[n,h*64+d]*WkT[(h*64+d)*357+c]  (col 356 gives qb)
__global__ __launch_bounds__(256) void k_qw(const float* q, const float* WkT, float* qw){
    __shared__ float qls[32*D];
    int blk = blockIdx.x;
    const float* qrow = q + (size_t)blk*32*D;
    for(int idx=threadIdx.x; idx<32*D; idx+=256) qls[idx]=qrow[idx];
    __syncthreads();
    for(int chunk=0; chunk<3; ++chunk){
        int oc = chunk*256 + threadIdx.x;
        if(oc >= QWROW) break;
        int hh = oc / HSTR; int c = oc - hh*HSTR;
        float acc[32];
        #pragma unroll
        for(int m=0;m<32;++m) acc[m]=0.f;
        const float* wp = WkT + (size_t)(hh*64)*HSTR + c;
        for(int d=0; d<64; ++d){
            float w = wp[(size_t)d*HSTR];
            #pragma unroll
            for(int m=0;m<32;++m) acc[m] += qls[m*D + hh*64 + d] * w;
        }
        float* qwp = qw + (size_t)blk*32*QWROW + oc;
        #pragma unroll
        for(int m=0;m<32;++m) qwp[(size_t)m*QWROW] = acc[m];
    }
}

// fused scores + masked softmax + av; one wave per node; av aliases qw (row-local)
template<int K, int CMIN, int S>
__global__ __launch_bounds__(64) void k_attn(float* qwav,
    const float* times, const float* nbr_times, const float* nbr_feats,
    const int* nbr_mask, const int* nbr_local, const float* zbuf,
    const float* time_w, const float* time_b){
    int n = blockIdx.x; int lane = threadIdx.x;
    float qwreg[NHD][S], qb[NHD];
    #pragma unroll
    for(int h=0;h<NHD;++h){
        qb[h] = qwav[(size_t)n*QWROW + h*HSTR + KIN];
        #pragma unroll
        for(int s=0;s<S;++s){
            int c = CMIN + s*64 + lane;
            qwreg[h][s] = (c < KIN) ? qwav[(size_t)n*QWROW + h*HSTR + c] : 0.f;
        }
    }
    float tw[S], tb[S];
    #pragma unroll
    for(int s=0;s<S;++s){
        int c = CMIN + s*64 + lane;
        if(c >= D+E && c < KIN){ tw[s]=time_w[c-(D+E)]; tb[s]=time_b[c-(D+E)]; }
        else { tw[s]=0.f; tb[s]=0.f; }
    }
    float tn = times[n];
    float kinreg[K][S];
    float sval[NHD][K];
    #pragma unroll
    for(int k=0;k<K;++k){
        float dt = tn - nbr_times[(size_t)n*K + k];
        const float* ef = nbr_feats + (size_t)(n*K+k)*E;
        const float* zf = (CMIN==0) ? (zbuf + (size_t)(nbr_local[(size_t)n*K+k] - N0C)*D) : (const float*)0;
        float p0=0.f, p1=0.f;
        #pragma unroll
        for(int s=0;s<S;++s){
            int c = CMIN + s*64 + lane;
            float kv = 0.f;
            if(c < KIN){
                if(CMIN==0 && c < D)      kv = zf[c];
                else if(c < D+E)          kv = ef[c-D];
                else                      kv = __cosf(dt*tw[s] + tb[s]);
            }
            kinreg[k][s] = kv;
            p0 += kv * qwreg[0][s];
            p1 += kv * qwreg[1][s];
        }
        #pragma unroll
        for(int off=32; off; off>>=1){ p0 += __shfl_xor(p0, off); p1 += __shfl_xor(p1, off); }
        int mk = nbr_mask[(size_t)n*K + k];
        sval[0][k] = (mk>0) ? (p0 + qb[0])*0.125f : -1e9f;
        sval[1][k] = (mk>0) ? (p1 + qb[1])*0.125f : -1e9f;
    }
    float a[NHD][K];
    #pragma unroll
    for(int h=0;h<NHD;++h){
        float mx = -1e30f;
        #pragma unroll
        for(int k=0;k<K;++k) mx = fmaxf(mx, sval[h][k]);
        float z=0.f;
        #pragma unroll
        for(int k=0;k<K;++k){ float e = __expf(sval[h][k]-mx); a[h][k]=e; z+=e; }
        float inv = 1.f/z;
        #pragma unroll
        for(int k=0;k<K;++k) a[h][k]*=inv;
    }
    #pragma unroll
    for(int h=0;h<NHD;++h)
      #pragma unroll
      for(int s=0;s<S;++s){
        int c = CMIN + s*64 + lane;
        if(c < KIN){
            float v=0.f;
            #pragma unroll
            for(int k=0;k<K;++k) v += a[h][k]*kinreg[k][s];
            qwav[(size_t)n*QWROW + h*HSTR + c] = v;
        }
      }
}

// out[n] = relu( sum_{h,c>=CMIN} av*Wvo + h@Wo_bot + cb )   (16 nodes / block)
template<int CMIN>
__global__ __launch_bounds__(256) void k_outproj(const float* av, const float* hbuf,
       const float* Wvo, const float* Wo, const float* cb, float* out){
    __shared__ float avls[16*QWROW];
    __shared__ float hls[16*D];
    int blk = blockIdx.x;
    const float* ap = av + (size_t)blk*16*QWROW;
    for(int idx=threadIdx.x; idx<16*QWROW; idx+=256) avls[idx]=ap[idx];
    const float* hp = hbuf + (size_t)blk*16*D;
    for(int idx=threadIdx.x; idx<16*D; idx+=256) hls[idx]=hp[idx];
    __syncthreads();
    int j = threadIdx.x & 127; int g = threadIdx.x >> 7;
    float acc[8];
    #pragma unroll
    for(int m=0;m<8;++m) acc[m]=0.f;
    for(int h=0; h<NHD; ++h){
        for(int c=CMIN; c<KIN; ++c){
            float w = Wvo[(size_t)(h*KIN + c)*D + j];
            #pragma unroll
            for(int m=0;m<8;++m) acc[m] += avls[(g*8+m)*QWROW + h*HSTR + c] * w;
        }
    }
    for(int c=0;c<D;++c){
        float w = Wo[(size_t)(D + c)*D + j];
        #pragma unroll
        for(int m=0;m<8;++m) acc[m] += hls[(g*8+m)*D + c] * w;
    }
    float cbj = cb[j];
    float* op = out + (size_t)blk*16*D;
    #pragma unroll
    for(int m=0;m<8;++m) op[(size_t)(g*8+m)*D + j] = fmaxf(acc[m] + cbj, 0.f);
}

// link prediction: both (src,dst) and (src,neg) per block
__global__ __launch_bounds__(128) void k_linkpred(const float* z0,
      const int* src,const int* dst,const int* neg,
      const float* Ws,const float* bs,const float* Wd,const float* bd,
      const float* Wo,const float* bo, float* out){
    __shared__ float zs[D], zd[D], zn[D];
    __shared__ float red[4];
    int b = blockIdx.x; int d = threadIdx.x;
    zs[d] = z0[(size_t)src[b]*D + d];
    zd[d] = z0[(size_t)dst[b]*D + d];
    zn[d] = z0[(size_t)neg[b]*D + d];
    __syncthreads();
    float ss=0.f, sdd=0.f, snn=0.f;
    for(int c=0;c<D;++c){
        float w1 = Ws[c*D + d], w2 = Wd[c*D + d];
        ss  += zs[c]*w1; sdd += zd[c]*w2; snn += zn[c]*w2;
    }
    float bb = bs[d] + bd[d];
    float h1 = fmaxf(ss + sdd + bb, 0.f);
    float h2 = fmaxf(ss + snn + bb, 0.f);
    float w = Wo[d];
    float v1 = h1*w, v2 = h2*w;
    #pragma unroll
    for(int off=32; off; off>>=1){ v1 += __shfl_xor(v1,off); v2 += __shfl_xor(v2,off); }
    int wid = d>>6;
    if((d&63)==0){ red[wid*2]=v1; red[wid*2+1]=v2; }
    __syncthreads();
    if(d==0){
        out[b]       = sigmoidf_(red[0]+red[2] + bo[0]);
        out[BSZ + b] = sigmoidf_(red[1]+red[3] + bo[0]);
    }
}

extern "C" void kernel_launch(void* const* d_in, const int* in_sizes, int n_in,
                              void* d_out, int out_size, void* d_ws, size_t ws_size,
                              hipStream_t stream) {
    const float* memory  = (const float*)d_in[0];
    const float* time_w  = (const float*)d_in[1];
    const float* time_b  = (const float*)d_in[2];
    const float* gWih    = (const float*)d_in[3];
    const float* gbih    = (const float*)d_in[4];
    const float* gWhh    = (const float*)d_in[5];
    const float* gbhh    = (const float*)d_in[6];
    const float* Wq0=(const float*)d_in[7],  *bq0=(const float*)d_in[8];
    const float* Wk0=(const float*)d_in[9],  *bk0=(const float*)d_in[10];
    const float* Wv0=(const float*)d_in[11], *bv0=(const float*)d_in[12];
    const float* Wo0=(const float*)d_in[13], *bo0=(const float*)d_in[14];
    const float* Wq1=(const float*)d_in[15], *bq1=(const float*)d_in[16];
    const float* Wk1=(const float*)d_in[17], *bk1=(const float*)d_in[18];
    const float* Wv1=(const float*)d_in[19], *bv1=(const float*)d_in[20];
    const float* Wo1=(const float*)d_in[21], *bo1=(const float*)d_in[22];
    const float* lpWs=(const float*)d_in[23], *lpbs=(const float*)d_in[24];
    const float* lpWd=(const float*)d_in[25], *lpbd=(const float*)d_in[26];
    const float* lpWo=(const float*)d_in[27], *lpbo=(const float*)d_in[28];
    const float* msgs    = (const float*)d_in[29];
    const float* times0  = (const float*)d_in[30];
    const float* ntimes0 = (const float*)d_in[31];
    const float* nfeats0 = (const float*)d_in[32];
    const float* times1  = (const float*)d_in[33];
    const float* ntimes1 = (const float*)d_in[34];
    const float* nfeats1 = (const float*)d_in[35];
    const int* msg_nids  = (const int*)d_in[36];
    const int* seed0     = (const int*)d_in[37];
    const int* seed1     = (const int*)d_in[38];
    const int* nbr_local0= (const int*)d_in[39];
    const int* nbr_mask0 = (const int*)d_in[40];
    const int* nbr_mask1 = (const int*)d_in[41];
    const int* src       = (const int*)d_in[42];
    const int* dst       = (const int*)d_in[43];
    const int* neg       = (const int*)d_in[44];

    char* ws = (char*)d_ws;
    size_t off = 0;
    auto alloc = [&](size_t bytes)->char*{
        char* p = ws + off;
        off += (bytes + 255) & ~(size_t)255;
        return p;
    };
    int*   map  = (int*)  alloc((size_t)NNC*4);
    float* upd  = (float*)alloc((size_t)MC*D*4);
    float* h1   = (float*)alloc((size_t)N1C*D*4);
    float* q1   = (float*)alloc((size_t)N1C*D*4);
    float* qw1  = (float*)alloc((size_t)N1C*QWROW*4);
    float* z1   = (float*)alloc((size_t)N1C*D*4);
    float* h0   = (float*)alloc((size_t)N0C*D*4);
    float* q0   = (float*)alloc((size_t)N0C*D*4);
    float* qw0  = (float*)alloc((size_t)N0C*QWROW*4);
    float* z0   = (float*)alloc((size_t)N0C*D*4);
    float* qc0  = (float*)alloc(512);
    float* qc1  = (float*)alloc(512);
    float* cb0  = (float*)alloc(512);
    float* cb1  = (float*)alloc(512);
    float* WkT0 = (float*)alloc((size_t)D*HSTR*4);
    float* WkT1 = (float*)alloc((size_t)D*HSTR*4);
    float* Wvo0 = (float*)alloc((size_t)2*KIN*D*4);
    float* Wvo1 = (float*)alloc((size_t)2*KIN*D*4);
    float* outp = (float*)d_out;

    // precompute
    k_pre_small<<<1,128,0,stream>>>(time_b, Wq0,bq0,Wq1,bq1, bv0,Wo0,bo0, bv1,Wo1,bo1,
                                    qc0,qc1,cb0,cb1);
    k_wkT<<<2*HSTR,128,0,stream>>>(Wk0,bk0,Wk1,bk1, WkT0,WkT1);
    k_wvo<<<2*2*KIN,128,0,stream>>>(Wv0,Wo0,Wv1,Wo1, Wvo0,Wvo1);

    // GRU memory update
    k_map_init<<<(NNC+255)/256,256,0,stream>>>(map);
    k_map_scatter<<<MC/256,256,0,stream>>>(msg_nids, map);
    k_gru<<<MC/16,128,0,stream>>>(msgs, memory, msg_nids, gWih,gbih,gWhh,gbhh, upd);

    // gather node states
    k_gather<<<(N1C*D)/256,256,0,stream>>>(seed1, map, memory, upd, h1, N1C*D);
    k_gather<<<(N0C*D)/256,256,0,stream>>>(seed0, map, memory, upd, h0, N0C*D);

    // hop 1
    k_qproj<<<N1C/32,256,0,stream>>>(h1, Wq1, qc1, q1);
    k_qw<<<N1C/32,256,0,stream>>>(q1, WkT1, qw1);
    k_attn<K1C,128,4><<<N1C,64,0,stream>>>(qw1, times1, ntimes1, nfeats1,
                                           nbr_mask1, (const int*)0, (const float*)0,
                                           time_w, time_b);
    k_outproj<128><<<N1C/16,256,0,stream>>>(qw1, h1, Wvo1, Wo1, cb1, z1);

    // hop 0
    k_qproj<<<N0C/32,256,0,stream>>>(h0, Wq0, qc0, q0);
    k_qw<<<N0C/32,256,0,stream>>>(q0, WkT0, qw0);
    k_attn<K0C,0,6><<<N0C,64,0,stream>>>(qw0, times0, ntimes0, nfeats0,
                                         nbr_mask0, nbr_local0, z1,
                                         time_w, time_b);
    k_outproj<0><<<N0C/16,256,0,stream>>>(qw0, h0, Wvo0, Wo0, cb0, z0);

    // link prediction
    k_linkpred<<<BSZ,128,0,stream>>>(z0, src,dst,neg, lpWs,lpbs,lpWd,lpbd, lpWo,lpbo, outp);
}